// Round 6
// baseline (204.150 us; speedup 1.0000x reference)
//
#include <hip/hip_runtime.h>
#include <hip/hip_bf16.h>

// SchNet CFConv, MI355X gfx950 — round 6.
// vs round 5 (203 us, cfconv 112 us):
//  * K1 split back to prep + in2f; in2f reads WiT from GLOBAL (no 32-way-conflict
//    LDS transpose, no 625x redundant Wi staging), 625 blocks.
//  * cfconv processes 4 atoms/block: W1T/W2T frags + biases hoisted out of the
//    atom loop; f2out batched over the 4 atoms so Wf2o is read once per block.
//
// d_ws layout (unsigned short elements):
//   [0     .. 4096 )  W1T bf16 [128 f][32 gpad]
//   [4096  .. 20480)  W2T bf16 [128 h][128 j]
//   [20480 .. 36864)  WiT bf16 [128 f][128 i]
//   [36864 .. +1.28M) yfeatb bf16 [10000][128]

#define NA 10000
#define NK 48
#define NF 128
#define AT 4      // atoms per cfconv block
#define DREP 40   // dRe LDS row pad (bf16)
#define HP   136  // H LDS row pad (bf16)

typedef __bf16 bf16x8 __attribute__((ext_vector_type(8)));
typedef float  f32x4  __attribute__((ext_vector_type(4)));

__device__ __forceinline__ unsigned short f2bs(float x) {
    return __builtin_bit_cast(unsigned short, (__bf16)x);
}
__device__ __forceinline__ float bs2f(unsigned short u) {
    return (float)__builtin_bit_cast(__bf16, u);
}
__device__ __forceinline__ float sspf(float v) {
    return fmaxf(v, 0.0f) + __logf(1.0f + __expf(-fabsf(v))) - 0.69314718056f;
}

// ---- K1: transpose-convert weights to bf16 in d_ws (144 blocks) ----
__global__ __launch_bounds__(256) void prep_weights(
    const float* __restrict__ W1,
    const float* __restrict__ W2,
    const float* __restrict__ Wi,
    unsigned short* __restrict__ wsb)
{
    int i = blockIdx.x * 256 + threadIdx.x;
    if (i < 4096) {                       // W1T[f][g], g padded to 32
        int f = i >> 5, g = i & 31;
        wsb[i] = (g < 25) ? f2bs(W1[g * NF + f]) : (unsigned short)0;
    } else if (i < 20480) {               // W2T[h][j] = W2[j][h]
        int j = i - 4096; int h = j >> 7, k = j & 127;
        wsb[i] = f2bs(W2[k * NF + h]);
    } else if (i < 36864) {               // WiT[f][i] = Wi[i][f]
        int j = i - 20480; int f = j >> 7, k = j & 127;
        wsb[i] = f2bs(Wi[k * NF + f]);
    }
}

// ---- K2: yfeatb = bf16(x @ W_in2f), 625 blocks x 16 rows, WiT from global ----
__global__ __launch_bounds__(256) void in2f_mfma(
    const float* __restrict__ x,
    const unsigned short* __restrict__ WiT,
    unsigned short* __restrict__ yfeatb)
{
    const int tid = threadIdx.x;
    const int w = tid >> 6;
    const int lane = tid & 63;
    const int r = lane & 15;
    const int q = lane >> 4;
    const int nt0 = w * 2;
    const int m0 = blockIdx.x * 16;   // 625*16 = 10000 exact

    bf16x8 a[4];
    #pragma unroll
    for (int ks = 0; ks < 4; ++ks) {
        const float4* xp = (const float4*)(x + (size_t)(m0 + r) * NF + ks * 32 + q * 8);
        float4 v0 = xp[0], v1 = xp[1];
        a[ks][0]=(__bf16)v0.x; a[ks][1]=(__bf16)v0.y; a[ks][2]=(__bf16)v0.z; a[ks][3]=(__bf16)v0.w;
        a[ks][4]=(__bf16)v1.x; a[ks][5]=(__bf16)v1.y; a[ks][6]=(__bf16)v1.z; a[ks][7]=(__bf16)v1.w;
    }

    f32x4 acc[2];
    acc[0] = (f32x4){0.f,0.f,0.f,0.f};
    acc[1] = (f32x4){0.f,0.f,0.f,0.f};
    #pragma unroll
    for (int ks = 0; ks < 4; ++ks) {
        bf16x8 b0 = *(const bf16x8*)(WiT + ((nt0    ) * 16 + r) * NF + ks * 32 + q * 8);
        bf16x8 b1 = *(const bf16x8*)(WiT + ((nt0 + 1) * 16 + r) * NF + ks * 32 + q * 8);
        acc[0] = __builtin_amdgcn_mfma_f32_16x16x32_bf16(a[ks], b0, acc[0], 0, 0, 0);
        acc[1] = __builtin_amdgcn_mfma_f32_16x16x32_bf16(a[ks], b1, acc[1], 0, 0, 0);
    }
    #pragma unroll
    for (int t = 0; t < 2; ++t)
        #pragma unroll
        for (int reg = 0; reg < 4; ++reg)
            yfeatb[(size_t)(m0 + q * 4 + reg) * NF + (nt0 + t) * 16 + r] = f2bs(acc[t][reg]);
}

// ---- K3: cfconv, 4 atoms/block, hoisted weights, batched f2out ----
__global__ __launch_bounds__(256) void cfconv_mfma(
    const float* __restrict__ dR,
    const float* __restrict__ dRe,
    const float* __restrict__ mask,
    const int*   __restrict__ nbr,
    const float* __restrict__ b1,
    const float* __restrict__ b2,
    const float* __restrict__ Wf2o,
    const float* __restrict__ bf2o,
    const unsigned short* __restrict__ W1T,
    const unsigned short* __restrict__ W2T,
    const unsigned short* __restrict__ yfeatb,
    float* __restrict__ out)
{
    __shared__ __align__(16) unsigned short s_dre[NK * DREP]; // 3840 B
    __shared__ __align__(16) unsigned short s_H[NK * HP];     // 13056 B
    __shared__ __align__(16) float s_y4[AT][NF];              // 2048 B
    __shared__ __align__(16) float s_part[AT][256];           // 4096 B
    __shared__ float s_cm[NK];
    __shared__ int   s_nb[NK];

    const int tid = threadIdx.x;
    const int w = tid >> 6;
    const int lane = tid & 63;
    const int r = lane & 15;
    const int q = lane >> 4;
    const int nt0 = w * 2;
    const int n0 = blockIdx.x * AT;

    // ---- hoisted weight fragments + biases (live across whole kernel) ----
    const float bias1a = b1[nt0 * 16 + r];
    const float bias1b = b1[nt0 * 16 + 16 + r];
    const float bias2a = b2[nt0 * 16 + r];
    const float bias2b = b2[nt0 * 16 + 16 + r];
    bf16x8 bfr0 = *(const bf16x8*)(W1T + ((nt0    ) * 16 + r) * 32 + q * 8);
    bf16x8 bfr1 = *(const bf16x8*)(W1T + ((nt0 + 1) * 16 + r) * 32 + q * 8);
    bf16x8 bw[2][4];
    #pragma unroll
    for (int t = 0; t < 2; ++t)
        #pragma unroll
        for (int ks = 0; ks < 4; ++ks)
            bw[t][ks] = *(const bf16x8*)(W2T + ((nt0 + t) * 16 + r) * NF + ks * 32 + q * 8);

    // ---- zero dre pad columns once (cols 25..39 stay 0 across atoms) ----
    {
        unsigned int* z = (unsigned int*)s_dre;
        for (int i = tid; i < NK * DREP / 2; i += 256) z[i] = 0u;
    }
    __syncthreads();

    for (int a = 0; a < AT; ++a) {
        const int n = n0 + a;

        // ---- staging: cm/nb + dRe rows ----
        if (tid < NK) {
            float d = dR[n * NK + tid];
            float m = mask[n * NK + tid];
            s_cm[tid] = (d <= 5.0f) ? m : 0.0f;
            s_nb[tid] = nbr[n * NK + tid] * NF;
        }
        {
            const float* dre = dRe + (size_t)n * (NK * 25);
            #pragma unroll
            for (int i = tid; i < NK * 25; i += 256) {
                int k = i / 25;
                int g = i - k * 25;
                s_dre[k * DREP + g] = f2bs(dre[i]);
            }
        }
        __syncthreads();

        // ---- stage 1: H = ssp(dRe @ W1 + b1) -> LDS ----
        #pragma unroll
        for (int mt = 0; mt < 3; ++mt) {
            bf16x8 af = *(const bf16x8*)(&s_dre[(mt * 16 + r) * DREP + q * 8]);
            f32x4 zf = (f32x4){0.f,0.f,0.f,0.f};
            f32x4 h0 = __builtin_amdgcn_mfma_f32_16x16x32_bf16(af, bfr0, zf, 0, 0, 0);
            f32x4 h1 = __builtin_amdgcn_mfma_f32_16x16x32_bf16(af, bfr1, zf, 0, 0, 0);
            #pragma unroll
            for (int reg = 0; reg < 4; ++reg) {
                int k = mt * 16 + q * 4 + reg;
                s_H[k * HP + nt0 * 16 + r]      = f2bs(sspf(h0[reg] + bias1a));
                s_H[k * HP + nt0 * 16 + 16 + r] = f2bs(sspf(h1[reg] + bias1b));
            }
        }
        __syncthreads();

        // ---- stage 2: A2 = H @ W2 ----
        f32x4 acc[3][2];
        #pragma unroll
        for (int mt = 0; mt < 3; ++mt) {
            acc[mt][0] = (f32x4){0.f,0.f,0.f,0.f};
            acc[mt][1] = (f32x4){0.f,0.f,0.f,0.f};
        }
        #pragma unroll
        for (int ks = 0; ks < 4; ++ks) {
            #pragma unroll
            for (int mt = 0; mt < 3; ++mt) {
                bf16x8 af = *(const bf16x8*)(&s_H[(mt * 16 + r) * HP + ks * 32 + q * 8]);
                acc[mt][0] = __builtin_amdgcn_mfma_f32_16x16x32_bf16(af, bw[0][ks], acc[mt][0], 0, 0, 0);
                acc[mt][1] = __builtin_amdgcn_mfma_f32_16x16x32_bf16(af, bw[1][ks], acc[mt][1], 0, 0, 0);
            }
        }

        // ---- gather + masked aggregation ----
        float part0 = 0.f, part1 = 0.f;
        const int h0i = nt0 * 16 + r;
        #pragma unroll
        for (int mt = 0; mt < 3; ++mt) {
            #pragma unroll
            for (int reg = 0; reg < 4; ++reg) {
                int k = mt * 16 + q * 4 + reg;
                float cmk = s_cm[k];
                int base = s_nb[k];
                part0 = fmaf(cmk * (acc[mt][0][reg] + bias2a), bs2f(yfeatb[base + h0i]), part0);
                part1 = fmaf(cmk * (acc[mt][1][reg] + bias2b), bs2f(yfeatb[base + h0i + 16]), part1);
            }
        }
        part0 += __shfl_xor(part0, 16);
        part0 += __shfl_xor(part0, 32);
        part1 += __shfl_xor(part1, 16);
        part1 += __shfl_xor(part1, 32);
        if (q == 0) {
            s_y4[a][h0i] = part0;
            s_y4[a][h0i + 16] = part1;
        }
        __syncthreads();   // protects s_H/s_cm/s_nb reuse next atom + s_y4 for f2out
    }

    // ---- batched f2out: out[n0+a] = ssp(y4[a] @ Wf2o + b), Wf2o read once ----
    {
        int f = tid & 127;
        int half = tid >> 7;
        float o0 = 0.f, o1 = 0.f, o2 = 0.f, o3 = 0.f;
        const float* wp = Wf2o + (size_t)(half * 64) * NF + f;
        const float* y0 = &s_y4[0][half * 64];
        const float* y1 = &s_y4[1][half * 64];
        const float* y2 = &s_y4[2][half * 64];
        const float* y3 = &s_y4[3][half * 64];
        #pragma unroll 8
        for (int i = 0; i < 64; ++i) {
            float wv = wp[(size_t)i * NF];
            o0 = fmaf(y0[i], wv, o0);
            o1 = fmaf(y1[i], wv, o1);
            o2 = fmaf(y2[i], wv, o2);
            o3 = fmaf(y3[i], wv, o3);
        }
        s_part[0][tid] = o0;
        s_part[1][tid] = o1;
        s_part[2][tid] = o2;
        s_part[3][tid] = o3;
    }
    __syncthreads();
    if (tid < NF) {
        float bo = bf2o[tid];
        #pragma unroll
        for (int a = 0; a < AT; ++a)
            out[(size_t)(n0 + a) * NF + tid] = sspf(s_part[a][tid] + s_part[a][tid + 128] + bo);
    }
}

extern "C" void kernel_launch(void* const* d_in, const int* in_sizes, int n_in,
                              void* d_out, int out_size, void* d_ws, size_t ws_size,
                              hipStream_t stream)
{
    const float* x    = (const float*)d_in[0];
    const float* dR   = (const float*)d_in[1];
    const float* dRe  = (const float*)d_in[2];
    const float* mask = (const float*)d_in[3];
    const int*   nbr  = (const int*)d_in[4];
    const float* W1   = (const float*)d_in[5];
    const float* b1   = (const float*)d_in[6];
    const float* W2   = (const float*)d_in[7];
    const float* b2   = (const float*)d_in[8];
    const float* Wi2f = (const float*)d_in[9];
    const float* Wf2o = (const float*)d_in[10];
    const float* bf2o = (const float*)d_in[11];
    float* out = (float*)d_out;

    unsigned short* wsb = (unsigned short*)d_ws;
    unsigned short* W1T    = wsb;            // 4096 elems
    unsigned short* W2T    = wsb + 4096;     // 16384 elems
    unsigned short* WiT    = wsb + 20480;    // 16384 elems
    unsigned short* yfeatb = wsb + 36864;    // 1,280,000 elems

    prep_weights<<<144, 256, 0, stream>>>(W1, W2, Wi2f, wsb);
    in2f_mfma<<<625, 256, 0, stream>>>(x, WiT, yfeatb);
    cfconv_mfma<<<NA / AT, 256, 0, stream>>>(dR, dRe, mask, nbr, b1, b2, Wf2o, bf2o,
                                             W1T, W2T, yfeatb, out);
}